// Round 13
// baseline (63.953 us; speedup 1.0000x reference)
//
#include <hip/hip_runtime.h>

#define BB 2
#define HKV 8
#define HH 32
#define TT 4096
#define NBLK 64
#define SCL 0.35355339059327373f   // 64^-0.25, folded into q and k
#define LOG2E 1.4426950408889634f

typedef __attribute__((ext_vector_type(8))) short short8;
typedef __attribute__((ext_vector_type(4))) float f32x4;
typedef unsigned int u32;

__device__ __forceinline__ unsigned short f2bf(float x) {
    union { float f; u32 u; } v; v.f = x;
    u32 r = v.u + 0x7fffu + ((v.u >> 16) & 1u);
    return (unsigned short)(r >> 16);
}
// HW packed f32->bf16 (RNE), one instruction
__device__ __forceinline__ u32 pk2(float lo, float hi) {
    u32 r;
    asm("v_cvt_pk_bf16_f32 %0, %1, %2" : "=v"(r) : "v"(lo), "v"(hi));
    return r;
}
__device__ __forceinline__ float bf2f(unsigned short b) {
    union { u32 u; float f; } v; v.u = ((u32)b) << 16; return v.f;
}
__device__ __forceinline__ f32x4 mfma16(short8 a, short8 b, f32x4 c) {
    return __builtin_amdgcn_mfma_f32_16x16x32_bf16(a, b, c, 0, 0, 0);
}
// 8-bf16 frag from a swizzled tile (LDS or global image): 128B row stride,
// byte ^= (row&7)<<4
__device__ __forceinline__ short8 ldsfrag(const char* base, int row, int off) {
    int b = (row << 7) + off;
    b ^= (row & 7) << 4;
    return *(const short8*)(base + b);
}
// C-frag pair (tiles t0,t1 spanning 32 X-rows, col=lane&15) -> A/B-frag with
// k = X = (lane>>4)*8 + j, same col. (Verified R2-R12.)
__device__ __forceinline__ short8 xform(f32x4 t0, f32x4 t1, int lane) {
    const int c = lane & 15, g = lane >> 4;
    u32 p00 = pk2(t0[0], t0[1]), p01 = pk2(t0[2], t0[3]);
    u32 p10 = pk2(t1[0], t1[1]), p11 = pk2(t1[2], t1[3]);
    int srcA = c + 32 * (g & 1);
    int srcB = srcA + 16;
    u32 a00 = (u32)__shfl((int)p00, srcA);
    u32 a01 = (u32)__shfl((int)p01, srcA);
    u32 a10 = (u32)__shfl((int)p10, srcA);
    u32 a11 = (u32)__shfl((int)p11, srcA);
    u32 b00 = (u32)__shfl((int)p00, srcB);
    u32 b01 = (u32)__shfl((int)p01, srcB);
    u32 b10 = (u32)__shfl((int)p10, srcB);
    u32 b11 = (u32)__shfl((int)p11, srcB);
    bool hi = (g & 2);
    union { u32 u[4]; short8 s; } r;
    r.u[0] = hi ? a10 : a00;
    r.u[1] = hi ? a11 : a01;
    r.u[2] = hi ? b10 : b00;
    r.u[3] = hi ? b11 : b01;
    return r.s;
}
__device__ __forceinline__ void gld16(const void* g, void* l) {
    __builtin_amdgcn_global_load_lds((const __attribute__((address_space(1))) u32*)g,
                                     (__attribute__((address_space(3))) u32*)l, 16, 0, 0);
}

// ---------------------------------------------------------------------------
// Phase 1: per (b,kv,n): build swizzled bf16 k (=k*SCL) and v^T LDS images,
// dump to global; compute phi_k via MFMA; write z_blk and S_blk^T image.
// (Unchanged from R5/R7/R9.)
// ---------------------------------------------------------------------------
__global__ __launch_bounds__(256, 4) void k_phase1(
        const float* __restrict__ kg, const float* __restrict__ vg,
        const float* __restrict__ pg,
        char* __restrict__ sblk, char* __restrict__ kbf, char* __restrict__ vbf,
        float* __restrict__ zg) {
    __shared__ __align__(16) char kb_s[8192];
    __shared__ __align__(16) char vt_s[8192];
    __shared__ float sqn_s[64];

    const int tid = threadIdx.x;
    const int bid = blockIdx.x;
    const size_t base = (size_t)bid * 4096;

#pragma unroll
    for (int j = 0; j < 4; ++j) {
        int i4 = tid + j * 256;
        int key = i4 >> 4, d0 = (i4 & 15) << 2;
        float4 fk = *(const float4*)(kg + base + key * 64 + d0);
        float s0 = fk.x * SCL, s1 = fk.y * SCL, s2 = fk.z * SCL, s3 = fk.w * SCL;
        int byte = (key << 7) + (d0 << 1); byte ^= (key & 7) << 4;
        *(uint2*)(kb_s + byte) = make_uint2(pk2(s0, s1), pk2(s2, s3));
        float ps = 0.5f * (s0 * s0 + s1 * s1 + s2 * s2 + s3 * s3);
        ps += __shfl_xor(ps, 1);
        ps += __shfl_xor(ps, 2);
        ps += __shfl_xor(ps, 4);
        ps += __shfl_xor(ps, 8);
        if ((tid & 15) == 0) sqn_s[key] = ps;
    }
    {
        int d = tid & 63, kq = tid >> 6;
        const float* vp = vg + base + (size_t)kq * 16 * 64 + d;
        union { unsigned short h[16]; uint4 q[2]; } pk;
#pragma unroll
        for (int i = 0; i < 16; ++i) pk.h[i] = f2bf(vp[i * 64]);
        int b0 = ((d << 7) + (kq << 5)) ^ ((d & 7) << 4);
        int b1 = ((d << 7) + (kq << 5) + 16) ^ ((d & 7) << 4);
        *(uint4*)(vt_s + b0) = pk.q[0];
        *(uint4*)(vt_s + b1) = pk.q[1];
    }
    __syncthreads();

    {
        int off = tid * 16;
        *(float4*)(kbf + (size_t)bid * 8192 + off) = *(const float4*)(kb_s + off);
        *(float4*)(kbf + (size_t)bid * 8192 + off + 4096) = *(const float4*)(kb_s + off + 4096);
        *(float4*)(vbf + (size_t)bid * 8192 + off) = *(const float4*)(vt_s + off);
        *(float4*)(vbf + (size_t)bid * 8192 + off + 4096) = *(const float4*)(vt_s + off + 4096);
    }

    const int lane = tid & 63, wv = tid >> 6;
    const int c = lane & 15, g = lane >> 4;
    const int fb = wv * 16;

    const float* prow = pg + (size_t)(fb + c) * 64;
    short8 pjb[2];
#pragma unroll
    for (int kt = 0; kt < 2; ++kt) {
        int d0 = kt * 32 + g * 8;
        float4 f0 = *(const float4*)(prow + d0);
        float4 f1 = *(const float4*)(prow + d0 + 4);
        union { u32 u[4]; short8 s; } r;
        r.u[0] = pk2(f0.x, f0.y); r.u[1] = pk2(f0.z, f0.w);
        r.u[2] = pk2(f1.x, f1.y); r.u[3] = pk2(f1.z, f1.w);
        pjb[kt] = r.s;
    }

    f32x4 pc[4];
    float zp = 0.f;
#pragma unroll
    for (int t = 0; t < 4; ++t) {
        f32x4 s = {0.f, 0.f, 0.f, 0.f};
        s = mfma16(ldsfrag(kb_s, t * 16 + c, g * 16), pjb[0], s);
        s = mfma16(ldsfrag(kb_s, t * 16 + c, g * 16 + 64), pjb[1], s);
#pragma unroll
        for (int r = 0; r < 4; ++r) {
            int w = t * 16 + g * 4 + r;
            float p = exp2f(fmaf(s[r] - sqn_s[w], LOG2E, -3.0f));
            s[r] = p;
            zp += p;
        }
        pc[t] = s;
    }
    zp += __shfl_xor(zp, 16);
    zp += __shfl_xor(zp, 32);
    if (lane < 16) zg[(size_t)bid * 64 + fb + c] = zp;

    short8 pb0 = xform(pc[0], pc[1], lane);
    short8 pb1 = xform(pc[2], pc[3], lane);

    char* so = sblk + (size_t)bid * 8192;
#pragma unroll
    for (int dt = 0; dt < 4; ++dt) {
        f32x4 s = {0.f, 0.f, 0.f, 0.f};
        s = mfma16(ldsfrag(vt_s, dt * 16 + c, g * 16), pb0, s);
        s = mfma16(ldsfrag(vt_s, dt * 16 + c, g * 16 + 64), pb1, s);
#pragma unroll
        for (int r = 0; r < 4; ++r) {
            int d = dt * 16 + g * 4 + r;
            int byte = ((d << 7) + ((fb + c) << 1)) ^ ((d & 7) << 4);
            *(unsigned short*)(so + byte) = f2bf(s[r]);
        }
    }
}

// ---------------------------------------------------------------------------
// Scan: shifted (delay-2) prefix over blocks, 8-wide batched loads; z; proj
// image. (Unchanged from R8/R9/R12.)
// ---------------------------------------------------------------------------
__global__ __launch_bounds__(256) void k_scan(char* __restrict__ sblk,
                                              float* __restrict__ zg,
                                              const float* __restrict__ pg,
                                              char* __restrict__ pbf) {
    const int tid = threadIdx.x;
    const int bx = blockIdx.x;
    if (bx < 128) {
        int pair = bx >> 3;
        int u = ((bx & 7) << 8) + tid;
        char* p = sblk + (size_t)pair * 64 * 8192 + (size_t)u * 4;
        float c0a = 0.f, c1a = 0.f, c0b = 0.f, c1b = 0.f;
        for (int n8 = 0; n8 < 64; n8 += 8) {
            u32 w[8];
#pragma unroll
            for (int j = 0; j < 8; ++j)
                w[j] = *(const u32*)(p + (size_t)(n8 + j) * 8192);
#pragma unroll
            for (int j = 0; j < 8; ++j) {
                *(u32*)(p + (size_t)(n8 + j) * 8192) = pk2(c0a, c0b);
                float va = bf2f((unsigned short)(w[j] & 0xffff));
                float vb = bf2f((unsigned short)(w[j] >> 16));
                c0a = c1a; c1a += va;
                c0b = c1b; c1b += vb;
            }
        }
    } else if (bx < 132) {
        int i = ((bx - 128) << 8) + tid;
        int pair = i >> 6, f = i & 63;
        float* zp = zg + (size_t)pair * 64 * 64 + f;
        float c0 = 0.f, c1 = 0.f;
        for (int n8 = 0; n8 < 64; n8 += 8) {
            float w[8];
#pragma unroll
            for (int j = 0; j < 8; ++j) w[j] = zp[(size_t)(n8 + j) * 64];
#pragma unroll
            for (int j = 0; j < 8; ++j) {
                zp[(size_t)(n8 + j) * 64] = c0;
                c0 = c1; c1 += w[j];
            }
        }
    } else {
#pragma unroll
        for (int j = 0; j < 4; ++j) {
            int i4 = tid + j * 256;
            int row = i4 >> 4, d0 = (i4 & 15) << 2;
            float4 f = *(const float4*)(pg + row * 64 + d0);
            int byte = ((row << 7) + (d0 << 1)) ^ ((row & 7) << 4);
            *(uint2*)(pbf + byte) = make_uint2(pk2(f.x, f.y), pk2(f.z, f.w));
        }
    }
}

// ---------------------------------------------------------------------------
// Main (R12 + two deltas): per (b,kv,n, head-pair), 2048 blocks, 4 waves,
// 2 GQA heads/wave. LDS 32KB all staged upfront, SINGLE barrier.
// Delta 1: S_used^T frags prefetched into regs IMMEDIATELY AFTER the barrier
//   (not across it - R10 spill lesson); ~1.5us of scores/phi work hides the
//   L2 latency before the epilogue consumes them. +32 VGPR, cap 168.
// Delta 2: s_setprio(1) around the epilogue MFMA cluster (post-barrier the
//   4 waves drift -> role diversity, T5's positive regime).
// Scalar out stores (exact WRITE_SIZE).
// ---------------------------------------------------------------------------
__global__ __launch_bounds__(256, 3) void k_main(
        const float* __restrict__ qg,
        const char* __restrict__ kbf, const char* __restrict__ vbf,
        const char* __restrict__ sbf, const char* __restrict__ pbf,
        const float* __restrict__ zg, float* __restrict__ outg) {
    __shared__ __align__(16) char smem[32768];

    const int tid = threadIdx.x;
    const int orig = blockIdx.x;                       // 2048 blocks
    const int bid = (orig & 7) * 256 + (orig >> 3);    // XCD-chunked (2048=8*256)
    const int pr = bid & 1;                            // head pair in group
    const int n = (bid >> 1) & 63;
    const int kv = (bid >> 7) & 7;
    const int b = bid >> 10;
    const int h0 = kv * 4 + pr * 2;                    // and h0+1
    const int iblk = ((b * HKV + kv) << 6) + n;
    const int lane = tid & 63, wv = tid >> 6;
    const int c = lane & 15, g = lane >> 4;
    const int qr = wv * 16 + c;
    const bool hasprev = (n > 0);

    // ---- q loads first (both heads; retire before gld16 queue)
    const size_t qrow0A = (size_t)(b * HH + h0) * TT + (size_t)n * 64;
    const size_t qrow0B = qrow0A + TT;                 // next head
    const float* qrowA = qg + (qrow0A + qr) * 64;
    const float* qrowB = qg + (qrow0B + qr) * 64;
    float4 qfA[4], qfB[4];
    qfA[0] = *(const float4*)(qrowA + g * 8);
    qfA[1] = *(const float4*)(qrowA + g * 8 + 4);
    qfA[2] = *(const float4*)(qrowA + 32 + g * 8);
    qfA[3] = *(const float4*)(qrowA + 32 + g * 8 + 4);
    qfB[0] = *(const float4*)(qrowB + g * 8);
    qfB[1] = *(const float4*)(qrowB + g * 8 + 4);
    qfB[2] = *(const float4*)(qrowB + 32 + g * 8);
    qfB[3] = *(const float4*)(qrowB + 32 + g * 8 + 4);

    // ---- stage ALL of K-prev | K-cur | V-prev | V-cur : 32 chunks, 8/wave
    {
        const char* gs[4] = {kbf + (size_t)(iblk - 1) * 8192, kbf + (size_t)iblk * 8192,
                             vbf + (size_t)(iblk - 1) * 8192, vbf + (size_t)iblk * 8192};
#pragma unroll
        for (int ci = 0; ci < 8; ++ci) {
            int cch = wv * 8 + ci;             // 0..31
            int seg = cch >> 3, off = (cch & 7) << 10;
            if (n == 0 && (seg == 0 || seg == 2)) continue;  // no prev block
            gld16(gs[seg] + off + lane * 16, smem + (seg << 13) + off);
        }
        if (n == 0) {  // V-prev zeros (a=0 * garbage NaN guard); K-prev masked
            uint4 zz = {0, 0, 0, 0};
            *(uint4*)(smem + 16384 + tid * 32) = zz;
            *(uint4*)(smem + 16384 + tid * 32 + 16) = zz;
        }
    }

    // ---- z (shared by both heads)
    float4 zv[4];
#pragma unroll
    for (int ft = 0; ft < 4; ++ft)
        zv[ft] = *(const float4*)(zg + (size_t)iblk * 64 + ft * 16 + g * 4);

    // ---- q -> bf16 frags + sqn, both heads (overlaps in-flight staging)
    float sqA = 0.f, sqB = 0.f;
    short8 qbA[2], qbB[2];
#pragma unroll
    for (int kt = 0; kt < 2; ++kt) {
        {
            float4 f0 = qfA[kt * 2], f1 = qfA[kt * 2 + 1];
            float s0 = f0.x * SCL, s1 = f0.y * SCL, s2 = f0.z * SCL, s3 = f0.w * SCL;
            float s4 = f1.x * SCL, s5 = f1.y * SCL, s6 = f1.z * SCL, s7 = f1.w * SCL;
            sqA += s0 * s0 + s1 * s1 + s2 * s2 + s3 * s3 + s4 * s4 + s5 * s5 + s6 * s6 + s7 * s7;
            union { u32 u[4]; short8 s; } r;
            r.u[0] = pk2(s0, s1); r.u[1] = pk2(s2, s3);
            r.u[2] = pk2(s4, s5); r.u[3] = pk2(s6, s7);
            qbA[kt] = r.s;
        }
        {
            float4 f0 = qfB[kt * 2], f1 = qfB[kt * 2 + 1];
            float s0 = f0.x * SCL, s1 = f0.y * SCL, s2 = f0.z * SCL, s3 = f0.w * SCL;
            float s4 = f1.x * SCL, s5 = f1.y * SCL, s6 = f1.z * SCL, s7 = f1.w * SCL;
            sqB += s0 * s0 + s1 * s1 + s2 * s2 + s3 * s3 + s4 * s4 + s5 * s5 + s6 * s6 + s7 * s7;
            union { u32 u[4]; short8 s; } r;
            r.u[0] = pk2(s0, s1); r.u[1] = pk2(s2, s3);
            r.u[2] = pk2(s4, s5); r.u[3] = pk2(s6, s7);
            qbB[kt] = r.s;
        }
    }
    sqA += __shfl_xor(sqA, 16);
    sqA += __shfl_xor(sqA, 32);
    sqB += __shfl_xor(sqB, 16);
    sqB += __shfl_xor(sqB, 32);
    const float sqnA = 0.5f * sqA, sqnB = 0.5f * sqB;

    __syncthreads();   // the ONLY barrier: all staging drained here

    // ---- Delta 1: S_used^T frags -> regs NOW (post-barrier; consumed ~1.5us
    // later in the epilogue, latency fully hidden under scores+phi)
    const char* stp = sbf + (size_t)iblk * 8192;
    short8 st[8];
#pragma unroll
    for (int dt = 0; dt < 4; ++dt) {
        st[dt * 2 + 0] = ldsfrag(stp, dt * 16 + c, g * 16);
        st[dt * 2 + 1] = ldsfrag(stp, dt * 16 + c, g * 16 + 64);
    }

    const char* K2 = smem;            // rows 0..127 (prev | cur)
    const char* VTP = smem + 16384;
    const char* VTC = smem + 24576;

    // ---- scores^T (8 key-tiles) for both heads
    short8 abA[4], abB[4];
    float asumA = 0.f, asumB = 0.f;
#pragma unroll
    for (int p = 0; p < 4; ++p) {
        f32x4 tA0, tA1, tB0, tB1;
#pragma unroll
        for (int half = 0; half < 2; ++half) {
            int t = p * 2 + half;
            short8 ka0 = ldsfrag(K2, t * 16 + c, g * 16);
            short8 ka1 = ldsfrag(K2, t * 16 + c, g * 16 + 64);
            f32x4 scA = {0.f, 0.f, 0.f, 0.f};
            scA = mfma16(ka0, qbA[0], scA);
            scA = mfma16(ka1, qbA[1], scA);
            f32x4 scB = {0.f, 0.f, 0.f, 0.f};
            scB = mfma16(ka0, qbB[0], scB);
            scB = mfma16(ka1, qbB[1], scB);
#pragma unroll
            for (int r = 0; r < 4; ++r) {
                int key = t * 16 + g * 4 + r;
                bool valid = (key >= 64) ? ((key - 64) <= qr) : hasprev;
                float aA = valid ? __expf(scA[r]) : 0.f;
                float aB = valid ? __expf(scB[r]) : 0.f;
                scA[r] = aA; asumA += aA;
                scB[r] = aB; asumB += aB;
            }
            if (half == 0) { tA0 = scA; tB0 = scB; } else { tA1 = scA; tB1 = scB; }
        }
        abA[p] = xform(tA0, tA1, lane);
        abB[p] = xform(tB0, tB1, lane);
    }
    asumA += __shfl_xor(asumA, 16);
    asumA += __shfl_xor(asumA, 32);
    asumB += __shfl_xor(asumB, 16);
    asumB += __shfl_xor(asumB, 32);

    // ---- phi_q^T (PJ frags from global image at use) + den_lin
    float dlA = 0.f, dlB = 0.f;
    short8 pbA[2], pbB[2];
#pragma unroll
    for (int pp = 0; pp < 2; ++pp) {
        f32x4 uA0, uA1, uB0, uB1;
#pragma unroll
        for (int half = 0; half < 2; ++half) {
            int ft = pp * 2 + half;
            short8 pj0 = ldsfrag(pbf, ft * 16 + c, g * 16);
            short8 pj1 = ldsfrag(pbf, ft * 16 + c, g * 16 + 64);
            f32x4 pfA = {0.f, 0.f, 0.f, 0.f};
            pfA = mfma16(pj0, qbA[0], pfA);
            pfA = mfma16(pj1, qbA[1], pfA);
            f32x4 pfB = {0.f, 0.f, 0.f, 0.f};
            pfB = mfma16(pj0, qbB[0], pfB);
            pfB = mfma16(pj1, qbB[1], pfB);
#pragma unroll
            for (int r = 0; r < 4; ++r) {
                float zr = ((const float*)&zv[ft])[r];
                float pvA = exp2f(fmaf(pfA[r] - sqnA, LOG2E, -3.0f));
                float pvB = exp2f(fmaf(pfB[r] - sqnB, LOG2E, -3.0f));
                pfA[r] = pvA; dlA += pvA * zr;
                pfB[r] = pvB; dlB += pvB * zr;
            }
            if (half == 0) { uA0 = pfA; uB0 = pfB; } else { uA1 = pfA; uB1 = pfB; }
        }
        pbA[pp] = xform(uA0, uA1, lane);
        pbB[pp] = xform(uB0, uB1, lane);
    }
    dlA += __shfl_xor(dlA, 16);
    dlA += __shfl_xor(dlA, 32);
    dlB += __shfl_xor(dlB, 16);
    dlB += __shfl_xor(dlB, 32);

    // ---- out^T = v^T·a^T + S^T·phi^T, both heads (S frags from regs)
    const float invA = 1.f / (asumA + dlA + 1e-6f);
    const float invB = 1.f / (asumB + dlB + 1e-6f);
    float* orowA = outg + (qrow0A + qr) * 64;
    float* orowB = outg + (qrow0B + qr) * 64;
    __builtin_amdgcn_s_setprio(1);    // Delta 2: favor this wave's MFMA run
#pragma unroll
    for (int dt = 0; dt < 4; ++dt) {
        short8 vp0 = ldsfrag(VTP, dt * 16 + c, g * 16);
        short8 vp1 = ldsfrag(VTP, dt * 16 + c, g * 16 + 64);
        short8 vc0 = ldsfrag(VTC, dt * 16 + c, g * 16);
        short8 vc1 = ldsfrag(VTC, dt * 16 + c, g * 16 + 64);
        f32x4 aA = {0.f, 0.f, 0.f, 0.f};
        aA = mfma16(vp0, abA[0], aA);
        aA = mfma16(vp1, abA[1], aA);
        aA = mfma16(vc0, abA[2], aA);
        aA = mfma16(vc1, abA[3], aA);
        aA = mfma16(st[dt * 2 + 0], pbA[0], aA);
        aA = mfma16(st[dt * 2 + 1], pbA[1], aA);
        f32x4 aB = {0.f, 0.f, 0.f, 0.f};
        aB = mfma16(vp0, abB[0], aB);
        aB = mfma16(vp1, abB[1], aB);
        aB = mfma16(vc0, abB[2], aB);
        aB = mfma16(vc1, abB[3], aB);
        aB = mfma16(st[dt * 2 + 0], pbB[0], aB);
        aB = mfma16(st[dt * 2 + 1], pbB[1], aB);
#pragma unroll
        for (int r = 0; r < 4; ++r) {
            orowA[dt * 16 + g * 4 + r] = aA[r] * invA;   // scalar: exact WRITE
            orowB[dt * 16 + g * 4 + r] = aB[r] * invB;
        }
    }
    __builtin_amdgcn_s_setprio(0);
}

// ---------------------------------------------------------------------------
extern "C" void kernel_launch(void* const* d_in, const int* in_sizes, int n_in,
                              void* d_out, int out_size, void* d_ws, size_t ws_size,
                              hipStream_t stream) {
    const float* q = (const float*)d_in[0];
    const float* k = (const float*)d_in[1];
    const float* v = (const float*)d_in[2];
    const float* proj = (const float*)d_in[3];
    float* out = (float*)d_out;

    char* ws = (char*)d_ws;
    char* sblk = ws;                                   // 8MB (in-place -> S_used)
    char* kbf = ws + (8u << 20);                       // 8MB
    char* vbf = ws + (16u << 20);                      // 8MB
    float* z = (float*)(ws + (24u << 20));             // 256KB
    char* pbf = ws + (24u << 20) + (256u << 10);       // 8KB

    k_phase1<<<dim3(1024), dim3(256), 0, stream>>>(k, v, proj, sblk, kbf, vbf, z);
    k_scan<<<dim3(133), dim3(256), 0, stream>>>(sblk, z, proj, pbf);
    k_main<<<dim3(2048), dim3(256), 0, stream>>>(q, kbf, vbf, sblk, pbf, z, out);
}

// Round 14
// 58.206 us; speedup vs baseline: 1.0987x; 1.0987x over previous
//
#include <hip/hip_runtime.h>

#define BB 2
#define HKV 8
#define HH 32
#define TT 4096
#define NBLK 64
#define SCL 0.35355339059327373f   // 64^-0.25, folded into q and k
#define LOG2E 1.4426950408889634f

typedef __attribute__((ext_vector_type(8))) short short8;
typedef __attribute__((ext_vector_type(4))) float f32x4;
typedef unsigned int u32;

__device__ __forceinline__ unsigned short f2bf(float x) {
    union { float f; u32 u; } v; v.f = x;
    u32 r = v.u + 0x7fffu + ((v.u >> 16) & 1u);
    return (unsigned short)(r >> 16);
}
// HW packed f32->bf16 (RNE), one instruction
__device__ __forceinline__ u32 pk2(float lo, float hi) {
    u32 r;
    asm("v_cvt_pk_bf16_f32 %0, %1, %2" : "=v"(r) : "v"(lo), "v"(hi));
    return r;
}
__device__ __forceinline__ float bf2f(unsigned short b) {
    union { u32 u; float f; } v; v.u = ((u32)b) << 16; return v.f;
}
__device__ __forceinline__ f32x4 mfma16(short8 a, short8 b, f32x4 c) {
    return __builtin_amdgcn_mfma_f32_16x16x32_bf16(a, b, c, 0, 0, 0);
}
// 8-bf16 frag from a swizzled tile (LDS or global image): 128B row stride,
// byte ^= (row&7)<<4
__device__ __forceinline__ short8 ldsfrag(const char* base, int row, int off) {
    int b = (row << 7) + off;
    b ^= (row & 7) << 4;
    return *(const short8*)(base + b);
}
// C-frag pair (tiles t0,t1 spanning 32 X-rows, col=lane&15) -> A/B-frag with
// k = X = (lane>>4)*8 + j, same col. (Verified R2-R13.)
__device__ __forceinline__ short8 xform(f32x4 t0, f32x4 t1, int lane) {
    const int c = lane & 15, g = lane >> 4;
    u32 p00 = pk2(t0[0], t0[1]), p01 = pk2(t0[2], t0[3]);
    u32 p10 = pk2(t1[0], t1[1]), p11 = pk2(t1[2], t1[3]);
    int srcA = c + 32 * (g & 1);
    int srcB = srcA + 16;
    u32 a00 = (u32)__shfl((int)p00, srcA);
    u32 a01 = (u32)__shfl((int)p01, srcA);
    u32 a10 = (u32)__shfl((int)p10, srcA);
    u32 a11 = (u32)__shfl((int)p11, srcA);
    u32 b00 = (u32)__shfl((int)p00, srcB);
    u32 b01 = (u32)__shfl((int)p01, srcB);
    u32 b10 = (u32)__shfl((int)p10, srcB);
    u32 b11 = (u32)__shfl((int)p11, srcB);
    bool hi = (g & 2);
    union { u32 u[4]; short8 s; } r;
    r.u[0] = hi ? a10 : a00;
    r.u[1] = hi ? a11 : a01;
    r.u[2] = hi ? b10 : b00;
    r.u[3] = hi ? b11 : b01;
    return r.s;
}
__device__ __forceinline__ void gld16(const void* g, void* l) {
    __builtin_amdgcn_global_load_lds((const __attribute__((address_space(1))) u32*)g,
                                     (__attribute__((address_space(3))) u32*)l, 16, 0, 0);
}

// ---------------------------------------------------------------------------
// Phase 1: per (b,kv,n): build swizzled bf16 k (=k*SCL) and v^T LDS images,
// dump to global; compute phi_k via MFMA; write z_blk and S_blk^T image.
// ---------------------------------------------------------------------------
__global__ __launch_bounds__(256, 4) void k_phase1(
        const float* __restrict__ kg, const float* __restrict__ vg,
        const float* __restrict__ pg,
        char* __restrict__ sblk, char* __restrict__ kbf, char* __restrict__ vbf,
        float* __restrict__ zg) {
    __shared__ __align__(16) char kb_s[8192];
    __shared__ __align__(16) char vt_s[8192];
    __shared__ float sqn_s[64];

    const int tid = threadIdx.x;
    const int bid = blockIdx.x;
    const size_t base = (size_t)bid * 4096;

#pragma unroll
    for (int j = 0; j < 4; ++j) {
        int i4 = tid + j * 256;
        int key = i4 >> 4, d0 = (i4 & 15) << 2;
        float4 fk = *(const float4*)(kg + base + key * 64 + d0);
        float s0 = fk.x * SCL, s1 = fk.y * SCL, s2 = fk.z * SCL, s3 = fk.w * SCL;
        int byte = (key << 7) + (d0 << 1); byte ^= (key & 7) << 4;
        *(uint2*)(kb_s + byte) = make_uint2(pk2(s0, s1), pk2(s2, s3));
        float ps = 0.5f * (s0 * s0 + s1 * s1 + s2 * s2 + s3 * s3);
        ps += __shfl_xor(ps, 1);
        ps += __shfl_xor(ps, 2);
        ps += __shfl_xor(ps, 4);
        ps += __shfl_xor(ps, 8);
        if ((tid & 15) == 0) sqn_s[key] = ps;
    }
    {
        int d = tid & 63, kq = tid >> 6;
        const float* vp = vg + base + (size_t)kq * 16 * 64 + d;
        union { unsigned short h[16]; uint4 q[2]; } pk;
#pragma unroll
        for (int i = 0; i < 16; ++i) pk.h[i] = f2bf(vp[i * 64]);
        int b0 = ((d << 7) + (kq << 5)) ^ ((d & 7) << 4);
        int b1 = ((d << 7) + (kq << 5) + 16) ^ ((d & 7) << 4);
        *(uint4*)(vt_s + b0) = pk.q[0];
        *(uint4*)(vt_s + b1) = pk.q[1];
    }
    __syncthreads();

    {
        int off = tid * 16;
        *(float4*)(kbf + (size_t)bid * 8192 + off) = *(const float4*)(kb_s + off);
        *(float4*)(kbf + (size_t)bid * 8192 + off + 4096) = *(const float4*)(kb_s + off + 4096);
        *(float4*)(vbf + (size_t)bid * 8192 + off) = *(const float4*)(vt_s + off);
        *(float4*)(vbf + (size_t)bid * 8192 + off + 4096) = *(const float4*)(vt_s + off + 4096);
    }

    const int lane = tid & 63, wv = tid >> 6;
    const int c = lane & 15, g = lane >> 4;
    const int fb = wv * 16;

    const float* prow = pg + (size_t)(fb + c) * 64;
    short8 pjb[2];
#pragma unroll
    for (int kt = 0; kt < 2; ++kt) {
        int d0 = kt * 32 + g * 8;
        float4 f0 = *(const float4*)(prow + d0);
        float4 f1 = *(const float4*)(prow + d0 + 4);
        union { u32 u[4]; short8 s; } r;
        r.u[0] = pk2(f0.x, f0.y); r.u[1] = pk2(f0.z, f0.w);
        r.u[2] = pk2(f1.x, f1.y); r.u[3] = pk2(f1.z, f1.w);
        pjb[kt] = r.s;
    }

    f32x4 pc[4];
    float zp = 0.f;
#pragma unroll
    for (int t = 0; t < 4; ++t) {
        f32x4 s = {0.f, 0.f, 0.f, 0.f};
        s = mfma16(ldsfrag(kb_s, t * 16 + c, g * 16), pjb[0], s);
        s = mfma16(ldsfrag(kb_s, t * 16 + c, g * 16 + 64), pjb[1], s);
#pragma unroll
        for (int r = 0; r < 4; ++r) {
            int w = t * 16 + g * 4 + r;
            float p = exp2f(fmaf(s[r] - sqn_s[w], LOG2E, -3.0f));
            s[r] = p;
            zp += p;
        }
        pc[t] = s;
    }
    zp += __shfl_xor(zp, 16);
    zp += __shfl_xor(zp, 32);
    if (lane < 16) zg[(size_t)bid * 64 + fb + c] = zp;

    short8 pb0 = xform(pc[0], pc[1], lane);
    short8 pb1 = xform(pc[2], pc[3], lane);

    char* so = sblk + (size_t)bid * 8192;
#pragma unroll
    for (int dt = 0; dt < 4; ++dt) {
        f32x4 s = {0.f, 0.f, 0.f, 0.f};
        s = mfma16(ldsfrag(vt_s, dt * 16 + c, g * 16), pb0, s);
        s = mfma16(ldsfrag(vt_s, dt * 16 + c, g * 16 + 64), pb1, s);
#pragma unroll
        for (int r = 0; r < 4; ++r) {
            int d = dt * 16 + g * 4 + r;
            int byte = ((d << 7) + ((fb + c) << 1)) ^ ((d & 7) << 4);
            *(unsigned short*)(so + byte) = f2bf(s[r]);
        }
    }
}

// ---------------------------------------------------------------------------
// Scan: shifted (delay-2) prefix over blocks, 8-wide batched loads; z; proj
// image.
// ---------------------------------------------------------------------------
__global__ __launch_bounds__(256) void k_scan(char* __restrict__ sblk,
                                              float* __restrict__ zg,
                                              const float* __restrict__ pg,
                                              char* __restrict__ pbf) {
    const int tid = threadIdx.x;
    const int bx = blockIdx.x;
    if (bx < 128) {
        int pair = bx >> 3;
        int u = ((bx & 7) << 8) + tid;
        char* p = sblk + (size_t)pair * 64 * 8192 + (size_t)u * 4;
        float c0a = 0.f, c1a = 0.f, c0b = 0.f, c1b = 0.f;
        for (int n8 = 0; n8 < 64; n8 += 8) {
            u32 w[8];
#pragma unroll
            for (int j = 0; j < 8; ++j)
                w[j] = *(const u32*)(p + (size_t)(n8 + j) * 8192);
#pragma unroll
            for (int j = 0; j < 8; ++j) {
                *(u32*)(p + (size_t)(n8 + j) * 8192) = pk2(c0a, c0b);
                float va = bf2f((unsigned short)(w[j] & 0xffff));
                float vb = bf2f((unsigned short)(w[j] >> 16));
                c0a = c1a; c1a += va;
                c0b = c1b; c1b += vb;
            }
        }
    } else if (bx < 132) {
        int i = ((bx - 128) << 8) + tid;
        int pair = i >> 6, f = i & 63;
        float* zp = zg + (size_t)pair * 64 * 64 + f;
        float c0 = 0.f, c1 = 0.f;
        for (int n8 = 0; n8 < 64; n8 += 8) {
            float w[8];
#pragma unroll
            for (int j = 0; j < 8; ++j) w[j] = zp[(size_t)(n8 + j) * 64];
#pragma unroll
            for (int j = 0; j < 8; ++j) {
                zp[(size_t)(n8 + j) * 64] = c0;
                c0 = c1; c1 += w[j];
            }
        }
    } else {
#pragma unroll
        for (int j = 0; j < 4; ++j) {
            int i4 = tid + j * 256;
            int row = i4 >> 4, d0 = (i4 & 15) << 2;
            float4 f = *(const float4*)(pg + row * 64 + d0);
            int byte = ((row << 7) + (d0 << 1)) ^ ((row & 7) << 4);
            *(uint2*)(pbf + byte) = make_uint2(pk2(f.x, f.y), pk2(f.z, f.w));
        }
    }
}

// ---------------------------------------------------------------------------
// Main (R9, measured best 59.0us): per (b,kv,n, head-pair), 2048 blocks.
// 4 waves = 4 q-tiles; each wave computes TWO GQA heads over its 16 q-rows,
// sharing all staged data (K/V/S/PJ/z). LDS 24KB:
//   [0:8K] K-prev (restaged to V-prev mid-kernel), [8K:16K] K-cur,
//   [16K:24K] V-cur. Every frag read feeds 2 MFMAs. S^T and PJ frags read
// AT USE from global images (reg-hoisting them spills - R10/R13 lessons).
// Scalar out stores (exact WRITE_SIZE). (256,3): cap 168 > ~90 demand.
// ---------------------------------------------------------------------------
__global__ __launch_bounds__(256, 3) void k_main(
        const float* __restrict__ qg,
        const char* __restrict__ kbf, const char* __restrict__ vbf,
        const char* __restrict__ sbf, const char* __restrict__ pbf,
        const float* __restrict__ zg, float* __restrict__ outg) {
    __shared__ __align__(16) char smem[24576];

    const int tid = threadIdx.x;
    const int orig = blockIdx.x;                       // 2048 blocks
    const int bid = (orig & 7) * 256 + (orig >> 3);    // XCD-chunked (2048=8*256)
    const int pr = bid & 1;                            // head pair in group
    const int n = (bid >> 1) & 63;
    const int kv = (bid >> 7) & 7;
    const int b = bid >> 10;
    const int h0 = kv * 4 + pr * 2;                    // and h0+1
    const int iblk = ((b * HKV + kv) << 6) + n;
    const int lane = tid & 63, wv = tid >> 6;
    const int c = lane & 15, g = lane >> 4;
    const int qr = wv * 16 + c;
    const bool hasprev = (n > 0);

    // ---- q loads first (both heads; retire before gld16 queue)
    const size_t qrow0A = (size_t)(b * HH + h0) * TT + (size_t)n * 64;
    const size_t qrow0B = qrow0A + TT;                 // next head
    const float* qrowA = qg + (qrow0A + qr) * 64;
    const float* qrowB = qg + (qrow0B + qr) * 64;
    float4 qfA[4], qfB[4];
    qfA[0] = *(const float4*)(qrowA + g * 8);
    qfA[1] = *(const float4*)(qrowA + g * 8 + 4);
    qfA[2] = *(const float4*)(qrowA + 32 + g * 8);
    qfA[3] = *(const float4*)(qrowA + 32 + g * 8 + 4);
    qfB[0] = *(const float4*)(qrowB + g * 8);
    qfB[1] = *(const float4*)(qrowB + g * 8 + 4);
    qfB[2] = *(const float4*)(qrowB + 32 + g * 8);
    qfB[3] = *(const float4*)(qrowB + 32 + g * 8 + 4);

    // ---- stage K-prev | K-cur | V-cur : 24 x 1KB chunks, 6 per wave
    {
        const char* gs[3] = {kbf + (size_t)(iblk - 1) * 8192, kbf + (size_t)iblk * 8192,
                             vbf + (size_t)iblk * 8192};
#pragma unroll
        for (int ci = 0; ci < 6; ++ci) {
            int cch = wv * 6 + ci;             // 0..23
            int seg = cch >> 3, off = (cch & 7) << 10;
            if (n == 0 && seg == 0) continue;  // no prev block
            gld16(gs[seg] + off + lane * 16, smem + (seg << 13) + off);
        }
        if (n == 0) {  // region0 zeros (V-prev NaN guard; K-prev masked)
            uint4 zz = {0, 0, 0, 0};
            *(uint4*)(smem + tid * 32) = zz;
            *(uint4*)(smem + tid * 32 + 16) = zz;
        }
    }

    // ---- z (shared by both heads)
    float4 zv[4];
#pragma unroll
    for (int ft = 0; ft < 4; ++ft)
        zv[ft] = *(const float4*)(zg + (size_t)iblk * 64 + ft * 16 + g * 4);

    // ---- q -> bf16 frags + sqn, both heads (overlaps in-flight staging)
    float sqA = 0.f, sqB = 0.f;
    short8 qbA[2], qbB[2];
#pragma unroll
    for (int kt = 0; kt < 2; ++kt) {
        {
            float4 f0 = qfA[kt * 2], f1 = qfA[kt * 2 + 1];
            float s0 = f0.x * SCL, s1 = f0.y * SCL, s2 = f0.z * SCL, s3 = f0.w * SCL;
            float s4 = f1.x * SCL, s5 = f1.y * SCL, s6 = f1.z * SCL, s7 = f1.w * SCL;
            sqA += s0 * s0 + s1 * s1 + s2 * s2 + s3 * s3 + s4 * s4 + s5 * s5 + s6 * s6 + s7 * s7;
            union { u32 u[4]; short8 s; } r;
            r.u[0] = pk2(s0, s1); r.u[1] = pk2(s2, s3);
            r.u[2] = pk2(s4, s5); r.u[3] = pk2(s6, s7);
            qbA[kt] = r.s;
        }
        {
            float4 f0 = qfB[kt * 2], f1 = qfB[kt * 2 + 1];
            float s0 = f0.x * SCL, s1 = f0.y * SCL, s2 = f0.z * SCL, s3 = f0.w * SCL;
            float s4 = f1.x * SCL, s5 = f1.y * SCL, s6 = f1.z * SCL, s7 = f1.w * SCL;
            sqB += s0 * s0 + s1 * s1 + s2 * s2 + s3 * s3 + s4 * s4 + s5 * s5 + s6 * s6 + s7 * s7;
            union { u32 u[4]; short8 s; } r;
            r.u[0] = pk2(s0, s1); r.u[1] = pk2(s2, s3);
            r.u[2] = pk2(s4, s5); r.u[3] = pk2(s6, s7);
            qbB[kt] = r.s;
        }
    }
    sqA += __shfl_xor(sqA, 16);
    sqA += __shfl_xor(sqA, 32);
    sqB += __shfl_xor(sqB, 16);
    sqB += __shfl_xor(sqB, 32);
    const float sqnA = 0.5f * sqA, sqnB = 0.5f * sqB;

    __syncthreads();

    const char* K2 = smem;            // rows 0..127 (prev | cur)
    const char* VTP = smem;           // after restage
    const char* VTC = smem + 16384;

    // ---- scores^T (8 key-tiles) for both heads; restage V-prev after p=1
    short8 abA[4], abB[4];
    float asumA = 0.f, asumB = 0.f;
#pragma unroll
    for (int p = 0; p < 4; ++p) {
        if (p == 2) {
            __syncthreads();          // all waves done reading K-prev
            if (hasprev) {
                const char* vp = vbf + (size_t)(iblk - 1) * 8192;
                gld16(vp + ((wv * 2 + 0) << 10) + lane * 16, smem + ((wv * 2 + 0) << 10));
                gld16(vp + ((wv * 2 + 1) << 10) + lane * 16, smem + ((wv * 2 + 1) << 10));
            }
        }
        f32x4 tA0, tA1, tB0, tB1;
#pragma unroll
        for (int half = 0; half < 2; ++half) {
            int t = p * 2 + half;
            short8 ka0 = ldsfrag(K2, t * 16 + c, g * 16);
            short8 ka1 = ldsfrag(K2, t * 16 + c, g * 16 + 64);
            f32x4 scA = {0.f, 0.f, 0.f, 0.f};
            scA = mfma16(ka0, qbA[0], scA);
            scA = mfma16(ka1, qbA[1], scA);
            f32x4 scB = {0.f, 0.f, 0.f, 0.f};
            scB = mfma16(ka0, qbB[0], scB);
            scB = mfma16(ka1, qbB[1], scB);
#pragma unroll
            for (int r = 0; r < 4; ++r) {
                int key = t * 16 + g * 4 + r;
                bool valid = (key >= 64) ? ((key - 64) <= qr) : hasprev;
                float aA = valid ? __expf(scA[r]) : 0.f;
                float aB = valid ? __expf(scB[r]) : 0.f;
                scA[r] = aA; asumA += aA;
                scB[r] = aB; asumB += aB;
            }
            if (half == 0) { tA0 = scA; tB0 = scB; } else { tA1 = scA; tB1 = scB; }
        }
        abA[p] = xform(tA0, tA1, lane);
        abB[p] = xform(tB0, tB1, lane);
    }
    asumA += __shfl_xor(asumA, 16);
    asumA += __shfl_xor(asumA, 32);
    asumB += __shfl_xor(asumB, 16);
    asumB += __shfl_xor(asumB, 32);

    // ---- phi_q^T (PJ frags from global image, each used twice) + den_lin
    float dlA = 0.f, dlB = 0.f;
    short8 pbA[2], pbB[2];
#pragma unroll
    for (int pp = 0; pp < 2; ++pp) {
        f32x4 uA0, uA1, uB0, uB1;
#pragma unroll
        for (int half = 0; half < 2; ++half) {
            int ft = pp * 2 + half;
            short8 pj0 = ldsfrag(pbf, ft * 16 + c, g * 16);
            short8 pj1 = ldsfrag(pbf, ft * 16 + c, g * 16 + 64);
            f32x4 pfA = {0.f, 0.f, 0.f, 0.f};
            pfA = mfma16(pj0, qbA[0], pfA);
            pfA = mfma16(pj1, qbA[1], pfA);
            f32x4 pfB = {0.f, 0.f, 0.f, 0.f};
            pfB = mfma16(pj0, qbB[0], pfB);
            pfB = mfma16(pj1, qbB[1], pfB);
#pragma unroll
            for (int r = 0; r < 4; ++r) {
                float zr = ((const float*)&zv[ft])[r];
                float pvA = exp2f(fmaf(pfA[r] - sqnA, LOG2E, -3.0f));
                float pvB = exp2f(fmaf(pfB[r] - sqnB, LOG2E, -3.0f));
                pfA[r] = pvA; dlA += pvA * zr;
                pfB[r] = pvB; dlB += pvB * zr;
            }
            if (half == 0) { uA0 = pfA; uB0 = pfB; } else { uA1 = pfA; uB1 = pfB; }
        }
        pbA[pp] = xform(uA0, uA1, lane);
        pbB[pp] = xform(uB0, uB1, lane);
    }
    dlA += __shfl_xor(dlA, 16);
    dlA += __shfl_xor(dlA, 32);
    dlB += __shfl_xor(dlB, 16);
    dlB += __shfl_xor(dlB, 32);

    __syncthreads();   // V-prev restage complete (barrier drains vmcnt)

    // ---- out^T = v^T·a^T + S^T·phi^T, both heads (frags read once)
    const char* stp = sbf + (size_t)iblk * 8192;
    const float invA = 1.f / (asumA + dlA + 1e-6f);
    const float invB = 1.f / (asumB + dlB + 1e-6f);
    float* orowA = outg + (qrow0A + qr) * 64;
    float* orowB = outg + (qrow0B + qr) * 64;
#pragma unroll
    for (int dt = 0; dt < 4; ++dt) {
        short8 vp0 = ldsfrag(VTP, dt * 16 + c, g * 16);
        short8 vp1 = ldsfrag(VTP, dt * 16 + c, g * 16 + 64);
        short8 vc0 = ldsfrag(VTC, dt * 16 + c, g * 16);
        short8 vc1 = ldsfrag(VTC, dt * 16 + c, g * 16 + 64);
        short8 st0 = ldsfrag(stp, dt * 16 + c, g * 16);
        short8 st1 = ldsfrag(stp, dt * 16 + c, g * 16 + 64);
        f32x4 aA = {0.f, 0.f, 0.f, 0.f};
        aA = mfma16(vp0, abA[0], aA);
        aA = mfma16(vp1, abA[1], aA);
        aA = mfma16(vc0, abA[2], aA);
        aA = mfma16(vc1, abA[3], aA);
        aA = mfma16(st0, pbA[0], aA);
        aA = mfma16(st1, pbA[1], aA);
        f32x4 aB = {0.f, 0.f, 0.f, 0.f};
        aB = mfma16(vp0, abB[0], aB);
        aB = mfma16(vp1, abB[1], aB);
        aB = mfma16(vc0, abB[2], aB);
        aB = mfma16(vc1, abB[3], aB);
        aB = mfma16(st0, pbB[0], aB);
        aB = mfma16(st1, pbB[1], aB);
#pragma unroll
        for (int r = 0; r < 4; ++r) {
            orowA[dt * 16 + g * 4 + r] = aA[r] * invA;   // scalar: exact WRITE
            orowB[dt * 16 + g * 4 + r] = aB[r] * invB;
        }
    }
}

// ---------------------------------------------------------------------------
extern "C" void kernel_launch(void* const* d_in, const int* in_sizes, int n_in,
                              void* d_out, int out_size, void* d_ws, size_t ws_size,
                              hipStream_t stream) {
    const float* q = (const float*)d_in[0];
    const float* k = (const float*)d_in[1];
    const float* v = (const float*)d_in[2];
    const float* proj = (const float*)d_in[3];
    float* out = (float*)d_out;

    char* ws = (char*)d_ws;
    char* sblk = ws;                                   // 8MB (in-place -> S_used)
    char* kbf = ws + (8u << 20);                       // 8MB
    char* vbf = ws + (16u << 20);                      // 8MB
    float* z = (float*)(ws + (24u << 20));             // 256KB
    char* pbf = ws + (24u << 20) + (256u << 10);       // 8KB

    k_phase1<<<dim3(1024), dim3(256), 0, stream>>>(k, v, proj, sblk, kbf, vbf, z);
    k_scan<<<dim3(133), dim3(256), 0, stream>>>(sblk, z, proj, pbf);
    k_main<<<dim3(2048), dim3(256), 0, stream>>>(q, kbf, vbf, sblk, pbf, z, out);
}

// Round 15
// 56.529 us; speedup vs baseline: 1.1313x; 1.0297x over previous
//
#include <hip/hip_runtime.h>

#define BB 2
#define HKV 8
#define HH 32
#define TT 4096
#define NBLK 64
#define SCL 0.35355339059327373f   // 64^-0.25, folded into q and k
#define LOG2E 1.4426950408889634f

typedef __attribute__((ext_vector_type(8))) short short8;
typedef __attribute__((ext_vector_type(4))) float f32x4;
typedef unsigned int u32;

__device__ __forceinline__ unsigned short f2bf(float x) {
    union { float f; u32 u; } v; v.f = x;
    u32 r = v.u + 0x7fffu + ((v.u >> 16) & 1u);
    return (unsigned short)(r >> 16);
}
// HW packed f32->bf16 (RNE), one instruction
__device__ __forceinline__ u32 pk2(float lo, float hi) {
    u32 r;
    asm("v_cvt_pk_bf16_f32 %0, %1, %2" : "=v"(r) : "v"(lo), "v"(hi));
    return r;
}
__device__ __forceinline__ float bf2f(unsigned short b) {
    union { u32 u; float f; } v; v.u = ((u32)b) << 16; return v.f;
}
__device__ __forceinline__ f32x4 mfma16(short8 a, short8 b, f32x4 c) {
    return __builtin_amdgcn_mfma_f32_16x16x32_bf16(a, b, c, 0, 0, 0);
}
// 8-bf16 frag from a swizzled tile (LDS or global image): 128B row stride,
// byte ^= (row&7)<<4
__device__ __forceinline__ short8 ldsfrag(const char* base, int row, int off) {
    int b = (row << 7) + off;
    b ^= (row & 7) << 4;
    return *(const short8*)(base + b);
}
// C-frag pair (tiles t0,t1 spanning 32 X-rows, col=lane&15) -> A/B-frag with
// k = X = (lane>>4)*8 + j, same col. (Verified R2-R14.)
__device__ __forceinline__ short8 xform(f32x4 t0, f32x4 t1, int lane) {
    const int c = lane & 15, g = lane >> 4;
    u32 p00 = pk2(t0[0], t0[1]), p01 = pk2(t0[2], t0[3]);
    u32 p10 = pk2(t1[0], t1[1]), p11 = pk2(t1[2], t1[3]);
    int srcA = c + 32 * (g & 1);
    int srcB = srcA + 16;
    u32 a00 = (u32)__shfl((int)p00, srcA);
    u32 a01 = (u32)__shfl((int)p01, srcA);
    u32 a10 = (u32)__shfl((int)p10, srcA);
    u32 a11 = (u32)__shfl((int)p11, srcA);
    u32 b00 = (u32)__shfl((int)p00, srcB);
    u32 b01 = (u32)__shfl((int)p01, srcB);
    u32 b10 = (u32)__shfl((int)p10, srcB);
    u32 b11 = (u32)__shfl((int)p11, srcB);
    bool hi = (g & 2);
    union { u32 u[4]; short8 s; } r;
    r.u[0] = hi ? a10 : a00;
    r.u[1] = hi ? a11 : a01;
    r.u[2] = hi ? b10 : b00;
    r.u[3] = hi ? b11 : b01;
    return r.s;
}
__device__ __forceinline__ void gld16(const void* g, void* l) {
    __builtin_amdgcn_global_load_lds((const __attribute__((address_space(1))) u32*)g,
                                     (__attribute__((address_space(3))) u32*)l, 16, 0, 0);
}

// ---------------------------------------------------------------------------
// Phase 1: per (b,kv,n): build swizzled bf16 k (=k*SCL) and v^T LDS images,
// dump to global; compute phi_k via MFMA; write z_blk and S_blk^T image.
// (Byte-identical to R14.)
// ---------------------------------------------------------------------------
__global__ __launch_bounds__(256, 4) void k_phase1(
        const float* __restrict__ kg, const float* __restrict__ vg,
        const float* __restrict__ pg,
        char* __restrict__ sblk, char* __restrict__ kbf, char* __restrict__ vbf,
        float* __restrict__ zg) {
    __shared__ __align__(16) char kb_s[8192];
    __shared__ __align__(16) char vt_s[8192];
    __shared__ float sqn_s[64];

    const int tid = threadIdx.x;
    const int bid = blockIdx.x;
    const size_t base = (size_t)bid * 4096;

#pragma unroll
    for (int j = 0; j < 4; ++j) {
        int i4 = tid + j * 256;
        int key = i4 >> 4, d0 = (i4 & 15) << 2;
        float4 fk = *(const float4*)(kg + base + key * 64 + d0);
        float s0 = fk.x * SCL, s1 = fk.y * SCL, s2 = fk.z * SCL, s3 = fk.w * SCL;
        int byte = (key << 7) + (d0 << 1); byte ^= (key & 7) << 4;
        *(uint2*)(kb_s + byte) = make_uint2(pk2(s0, s1), pk2(s2, s3));
        float ps = 0.5f * (s0 * s0 + s1 * s1 + s2 * s2 + s3 * s3);
        ps += __shfl_xor(ps, 1);
        ps += __shfl_xor(ps, 2);
        ps += __shfl_xor(ps, 4);
        ps += __shfl_xor(ps, 8);
        if ((tid & 15) == 0) sqn_s[key] = ps;
    }
    {
        int d = tid & 63, kq = tid >> 6;
        const float* vp = vg + base + (size_t)kq * 16 * 64 + d;
        union { unsigned short h[16]; uint4 q[2]; } pk;
#pragma unroll
        for (int i = 0; i < 16; ++i) pk.h[i] = f2bf(vp[i * 64]);
        int b0 = ((d << 7) + (kq << 5)) ^ ((d & 7) << 4);
        int b1 = ((d << 7) + (kq << 5) + 16) ^ ((d & 7) << 4);
        *(uint4*)(vt_s + b0) = pk.q[0];
        *(uint4*)(vt_s + b1) = pk.q[1];
    }
    __syncthreads();

    {
        int off = tid * 16;
        *(float4*)(kbf + (size_t)bid * 8192 + off) = *(const float4*)(kb_s + off);
        *(float4*)(kbf + (size_t)bid * 8192 + off + 4096) = *(const float4*)(kb_s + off + 4096);
        *(float4*)(vbf + (size_t)bid * 8192 + off) = *(const float4*)(vt_s + off);
        *(float4*)(vbf + (size_t)bid * 8192 + off + 4096) = *(const float4*)(vt_s + off + 4096);
    }

    const int lane = tid & 63, wv = tid >> 6;
    const int c = lane & 15, g = lane >> 4;
    const int fb = wv * 16;

    const float* prow = pg + (size_t)(fb + c) * 64;
    short8 pjb[2];
#pragma unroll
    for (int kt = 0; kt < 2; ++kt) {
        int d0 = kt * 32 + g * 8;
        float4 f0 = *(const float4*)(prow + d0);
        float4 f1 = *(const float4*)(prow + d0 + 4);
        union { u32 u[4]; short8 s; } r;
        r.u[0] = pk2(f0.x, f0.y); r.u[1] = pk2(f0.z, f0.w);
        r.u[2] = pk2(f1.x, f1.y); r.u[3] = pk2(f1.z, f1.w);
        pjb[kt] = r.s;
    }

    f32x4 pc[4];
    float zp = 0.f;
#pragma unroll
    for (int t = 0; t < 4; ++t) {
        f32x4 s = {0.f, 0.f, 0.f, 0.f};
        s = mfma16(ldsfrag(kb_s, t * 16 + c, g * 16), pjb[0], s);
        s = mfma16(ldsfrag(kb_s, t * 16 + c, g * 16 + 64), pjb[1], s);
#pragma unroll
        for (int r = 0; r < 4; ++r) {
            int w = t * 16 + g * 4 + r;
            float p = exp2f(fmaf(s[r] - sqn_s[w], LOG2E, -3.0f));
            s[r] = p;
            zp += p;
        }
        pc[t] = s;
    }
    zp += __shfl_xor(zp, 16);
    zp += __shfl_xor(zp, 32);
    if (lane < 16) zg[(size_t)bid * 64 + fb + c] = zp;

    short8 pb0 = xform(pc[0], pc[1], lane);
    short8 pb1 = xform(pc[2], pc[3], lane);

    char* so = sblk + (size_t)bid * 8192;
#pragma unroll
    for (int dt = 0; dt < 4; ++dt) {
        f32x4 s = {0.f, 0.f, 0.f, 0.f};
        s = mfma16(ldsfrag(vt_s, dt * 16 + c, g * 16), pb0, s);
        s = mfma16(ldsfrag(vt_s, dt * 16 + c, g * 16 + 64), pb1, s);
#pragma unroll
        for (int r = 0; r < 4; ++r) {
            int d = dt * 16 + g * 4 + r;
            int byte = ((d << 7) + ((fb + c) << 1)) ^ ((d & 7) << 4);
            *(unsigned short*)(so + byte) = f2bf(s[r]);
        }
    }
}

// ---------------------------------------------------------------------------
// Scan (R15 delta): full 64-deep register batch per thread - all 64 loads in
// flight at once (1 latency round instead of 8), then register-resident
// shifted prefix with fire-and-forget stores. z-scan likewise.
// Block 132 builds the proj image (unchanged).
// ---------------------------------------------------------------------------
__global__ __launch_bounds__(256) void k_scan(char* __restrict__ sblk,
                                              float* __restrict__ zg,
                                              const float* __restrict__ pg,
                                              char* __restrict__ pbf) {
    const int tid = threadIdx.x;
    const int bx = blockIdx.x;
    if (bx < 128) {
        int pair = bx >> 3;
        int u = ((bx & 7) << 8) + tid;
        char* p = sblk + (size_t)pair * 64 * 8192 + (size_t)u * 4;
        u32 w[64];
#pragma unroll
        for (int j = 0; j < 64; ++j)
            w[j] = *(const u32*)(p + (size_t)j * 8192);
        float c0a = 0.f, c1a = 0.f, c0b = 0.f, c1b = 0.f;
#pragma unroll
        for (int j = 0; j < 64; ++j) {
            *(u32*)(p + (size_t)j * 8192) = pk2(c0a, c0b);
            float va = bf2f((unsigned short)(w[j] & 0xffff));
            float vb = bf2f((unsigned short)(w[j] >> 16));
            c0a = c1a; c1a += va;
            c0b = c1b; c1b += vb;
        }
    } else if (bx < 132) {
        int i = ((bx - 128) << 8) + tid;
        int pair = i >> 6, f = i & 63;
        float* zp = zg + (size_t)pair * 64 * 64 + f;
        float w[64];
#pragma unroll
        for (int j = 0; j < 64; ++j) w[j] = zp[(size_t)j * 64];
        float c0 = 0.f, c1 = 0.f;
#pragma unroll
        for (int j = 0; j < 64; ++j) {
            zp[(size_t)j * 64] = c0;
            c0 = c1; c1 += w[j];
        }
    } else {
#pragma unroll
        for (int j = 0; j < 4; ++j) {
            int i4 = tid + j * 256;
            int row = i4 >> 4, d0 = (i4 & 15) << 2;
            float4 f = *(const float4*)(pg + row * 64 + d0);
            int byte = ((row << 7) + (d0 << 1)) ^ ((row & 7) << 4);
            *(uint2*)(pbf + byte) = make_uint2(pk2(f.x, f.y), pk2(f.z, f.w));
        }
    }
}

// ---------------------------------------------------------------------------
// Main (R9/R14, measured best 58.2us): per (b,kv,n, head-pair), 2048 blocks.
// 4 waves = 4 q-tiles; each wave computes TWO GQA heads over its 16 q-rows,
// sharing all staged data (K/V/S/PJ/z). LDS 24KB:
//   [0:8K] K-prev (restaged to V-prev mid-kernel), [8K:16K] K-cur,
//   [16K:24K] V-cur. Every frag read feeds 2 MFMAs. S^T and PJ frags read
// AT USE from global images (reg-hoisting them spills - R10/R13 lessons).
// Scalar out stores (exact WRITE_SIZE). (256,3): cap 168 > ~90 demand.
// (Byte-identical to R14.)
// ---------------------------------------------------------------------------
__global__ __launch_bounds__(256, 3) void k_main(
        const float* __restrict__ qg,
        const char* __restrict__ kbf, const char* __restrict__ vbf,
        const char* __restrict__ sbf, const char* __restrict__ pbf,
        const float* __restrict__ zg, float* __restrict__ outg) {
    __shared__ __align__(16) char smem[24576];

    const int tid = threadIdx.x;
    const int orig = blockIdx.x;                       // 2048 blocks
    const int bid = (orig & 7) * 256 + (orig >> 3);    // XCD-chunked (2048=8*256)
    const int pr = bid & 1;                            // head pair in group
    const int n = (bid >> 1) & 63;
    const int kv = (bid >> 7) & 7;
    const int b = bid >> 10;
    const int h0 = kv * 4 + pr * 2;                    // and h0+1
    const int iblk = ((b * HKV + kv) << 6) + n;
    const int lane = tid & 63, wv = tid >> 6;
    const int c = lane & 15, g = lane >> 4;
    const int qr = wv * 16 + c;
    const bool hasprev = (n > 0);

    // ---- q loads first (both heads; retire before gld16 queue)
    const size_t qrow0A = (size_t)(b * HH + h0) * TT + (size_t)n * 64;
    const size_t qrow0B = qrow0A + TT;                 // next head
    const float* qrowA = qg + (qrow0A + qr) * 64;
    const float* qrowB = qg + (qrow0B + qr) * 64;
    float4 qfA[4], qfB[4];
    qfA[0] = *(const float4*)(qrowA + g * 8);
    qfA[1] = *(const float4*)(qrowA + g * 8 + 4);
    qfA[2] = *(const float4*)(qrowA + 32 + g * 8);
    qfA[3] = *(const float4*)(qrowA + 32 + g * 8 + 4);
    qfB[0] = *(const float4*)(qrowB + g * 8);
    qfB[1] = *(const float4*)(qrowB + g * 8 + 4);
    qfB[2] = *(const float4*)(qrowB + 32 + g * 8);
    qfB[3] = *(const float4*)(qrowB + 32 + g * 8 + 4);

    // ---- stage K-prev | K-cur | V-cur : 24 x 1KB chunks, 6 per wave
    {
        const char* gs[3] = {kbf + (size_t)(iblk - 1) * 8192, kbf + (size_t)iblk * 8192,
                             vbf + (size_t)iblk * 8192};
#pragma unroll
        for (int ci = 0; ci < 6; ++ci) {
            int cch = wv * 6 + ci;             // 0..23
            int seg = cch >> 3, off = (cch & 7) << 10;
            if (n == 0 && seg == 0) continue;  // no prev block
            gld16(gs[seg] + off + lane * 16, smem + (seg << 13) + off);
        }
        if (n == 0) {  // region0 zeros (V-prev NaN guard; K-prev masked)
            uint4 zz = {0, 0, 0, 0};
            *(uint4*)(smem + tid * 32) = zz;
            *(uint4*)(smem + tid * 32 + 16) = zz;
        }
    }

    // ---- z (shared by both heads)
    float4 zv[4];
#pragma unroll
    for (int ft = 0; ft < 4; ++ft)
        zv[ft] = *(const float4*)(zg + (size_t)iblk * 64 + ft * 16 + g * 4);

    // ---- q -> bf16 frags + sqn, both heads (overlaps in-flight staging)
    float sqA = 0.f, sqB = 0.f;
    short8 qbA[2], qbB[2];
#pragma unroll
    for (int kt = 0; kt < 2; ++kt) {
        {
            float4 f0 = qfA[kt * 2], f1 = qfA[kt * 2 + 1];
            float s0 = f0.x * SCL, s1 = f0.y * SCL, s2 = f0.z * SCL, s3 = f0.w * SCL;
            float s4 = f1.x * SCL, s5 = f1.y * SCL, s6 = f1.z * SCL, s7 = f1.w * SCL;
            sqA += s0 * s0 + s1 * s1 + s2 * s2 + s3 * s3 + s4 * s4 + s5 * s5 + s6 * s6 + s7 * s7;
            union { u32 u[4]; short8 s; } r;
            r.u[0] = pk2(s0, s1); r.u[1] = pk2(s2, s3);
            r.u[2] = pk2(s4, s5); r.u[3] = pk2(s6, s7);
            qbA[kt] = r.s;
        }
        {
            float4 f0 = qfB[kt * 2], f1 = qfB[kt * 2 + 1];
            float s0 = f0.x * SCL, s1 = f0.y * SCL, s2 = f0.z * SCL, s3 = f0.w * SCL;
            float s4 = f1.x * SCL, s5 = f1.y * SCL, s6 = f1.z * SCL, s7 = f1.w * SCL;
            sqB += s0 * s0 + s1 * s1 + s2 * s2 + s3 * s3 + s4 * s4 + s5 * s5 + s6 * s6 + s7 * s7;
            union { u32 u[4]; short8 s; } r;
            r.u[0] = pk2(s0, s1); r.u[1] = pk2(s2, s3);
            r.u[2] = pk2(s4, s5); r.u[3] = pk2(s6, s7);
            qbB[kt] = r.s;
        }
    }
    sqA += __shfl_xor(sqA, 16);
    sqA += __shfl_xor(sqA, 32);
    sqB += __shfl_xor(sqB, 16);
    sqB += __shfl_xor(sqB, 32);
    const float sqnA = 0.5f * sqA, sqnB = 0.5f * sqB;

    __syncthreads();

    const char* K2 = smem;            // rows 0..127 (prev | cur)
    const char* VTP = smem;           // after restage
    const char* VTC = smem + 16384;

    // ---- scores^T (8 key-tiles) for both heads; restage V-prev after p=1
    short8 abA[4], abB[4];
    float asumA = 0.f, asumB = 0.f;
#pragma unroll
    for (int p = 0; p < 4; ++p) {
        if (p == 2) {
            __syncthreads();          // all waves done reading K-prev
            if (hasprev) {
                const char* vp = vbf + (size_t)(iblk - 1) * 8192;
                gld16(vp + ((wv * 2 + 0) << 10) + lane * 16, smem + ((wv * 2 + 0) << 10));
                gld16(vp + ((wv * 2 + 1) << 10) + lane * 16, smem + ((wv * 2 + 1) << 10));
            }
        }
        f32x4 tA0, tA1, tB0, tB1;
#pragma unroll
        for (int half = 0; half < 2; ++half) {
            int t = p * 2 + half;
            short8 ka0 = ldsfrag(K2, t * 16 + c, g * 16);
            short8 ka1 = ldsfrag(K2, t * 16 + c, g * 16 + 64);
            f32x4 scA = {0.f, 0.f, 0.f, 0.f};
            scA = mfma16(ka0, qbA[0], scA);
            scA = mfma16(ka1, qbA[1], scA);
            f32x4 scB = {0.f, 0.f, 0.f, 0.f};
            scB = mfma16(ka0, qbB[0], scB);
            scB = mfma16(ka1, qbB[1], scB);
#pragma unroll
            for (int r = 0; r < 4; ++r) {
                int key = t * 16 + g * 4 + r;
                bool valid = (key >= 64) ? ((key - 64) <= qr) : hasprev;
                float aA = valid ? __expf(scA[r]) : 0.f;
                float aB = valid ? __expf(scB[r]) : 0.f;
                scA[r] = aA; asumA += aA;
                scB[r] = aB; asumB += aB;
            }
            if (half == 0) { tA0 = scA; tB0 = scB; } else { tA1 = scA; tB1 = scB; }
        }
        abA[p] = xform(tA0, tA1, lane);
        abB[p] = xform(tB0, tB1, lane);
    }
    asumA += __shfl_xor(asumA, 16);
    asumA += __shfl_xor(asumA, 32);
    asumB += __shfl_xor(asumB, 16);
    asumB += __shfl_xor(asumB, 32);

    // ---- phi_q^T (PJ frags from global image, each used twice) + den_lin
    float dlA = 0.f, dlB = 0.f;
    short8 pbA[2], pbB[2];
#pragma unroll
    for (int pp = 0; pp < 2; ++pp) {
        f32x4 uA0, uA1, uB0, uB1;
#pragma unroll
        for (int half = 0; half < 2; ++half) {
            int ft = pp * 2 + half;
            short8 pj0 = ldsfrag(pbf, ft * 16 + c, g * 16);
            short8 pj1 = ldsfrag(pbf, ft * 16 + c, g * 16 + 64);
            f32x4 pfA = {0.f, 0.f, 0.f, 0.f};
            pfA = mfma16(pj0, qbA[0], pfA);
            pfA = mfma16(pj1, qbA[1], pfA);
            f32x4 pfB = {0.f, 0.f, 0.f, 0.f};
            pfB = mfma16(pj0, qbB[0], pfB);
            pfB = mfma16(pj1, qbB[1], pfB);
#pragma unroll
            for (int r = 0; r < 4; ++r) {
                float zr = ((const float*)&zv[ft])[r];
                float pvA = exp2f(fmaf(pfA[r] - sqnA, LOG2E, -3.0f));
                float pvB = exp2f(fmaf(pfB[r] - sqnB, LOG2E, -3.0f));
                pfA[r] = pvA; dlA += pvA * zr;
                pfB[r] = pvB; dlB += pvB * zr;
            }
            if (half == 0) { uA0 = pfA; uB0 = pfB; } else { uA1 = pfA; uB1 = pfB; }
        }
        pbA[pp] = xform(uA0, uA1, lane);
        pbB[pp] = xform(uB0, uB1, lane);
    }
    dlA += __shfl_xor(dlA, 16);
    dlA += __shfl_xor(dlA, 32);
    dlB += __shfl_xor(dlB, 16);
    dlB += __shfl_xor(dlB, 32);

    __syncthreads();   // V-prev restage complete (barrier drains vmcnt)

    // ---- out^T = v^T·a^T + S^T·phi^T, both heads (frags read once)
    const char* stp = sbf + (size_t)iblk * 8192;
    const float invA = 1.f / (asumA + dlA + 1e-6f);
    const float invB = 1.f / (asumB + dlB + 1e-6f);
    float* orowA = outg + (qrow0A + qr) * 64;
    float* orowB = outg + (qrow0B + qr) * 64;
#pragma unroll
    for (int dt = 0; dt < 4; ++dt) {
        short8 vp0 = ldsfrag(VTP, dt * 16 + c, g * 16);
        short8 vp1 = ldsfrag(VTP, dt * 16 + c, g * 16 + 64);
        short8 vc0 = ldsfrag(VTC, dt * 16 + c, g * 16);
        short8 vc1 = ldsfrag(VTC, dt * 16 + c, g * 16 + 64);
        short8 st0 = ldsfrag(stp, dt * 16 + c, g * 16);
        short8 st1 = ldsfrag(stp, dt * 16 + c, g * 16 + 64);
        f32x4 aA = {0.f, 0.f, 0.f, 0.f};
        aA = mfma16(vp0, abA[0], aA);
        aA = mfma16(vp1, abA[1], aA);
        aA = mfma16(vc0, abA[2], aA);
        aA = mfma16(vc1, abA[3], aA);
        aA = mfma16(st0, pbA[0], aA);
        aA = mfma16(st1, pbA[1], aA);
        f32x4 aB = {0.f, 0.f, 0.f, 0.f};
        aB = mfma16(vp0, abB[0], aB);
        aB = mfma16(vp1, abB[1], aB);
        aB = mfma16(vc0, abB[2], aB);
        aB = mfma16(vc1, abB[3], aB);
        aB = mfma16(st0, pbB[0], aB);
        aB = mfma16(st1, pbB[1], aB);
#pragma unroll
        for (int r = 0; r < 4; ++r) {
            orowA[dt * 16 + g * 4 + r] = aA[r] * invA;   // scalar: exact WRITE
            orowB[dt * 16 + g * 4 + r] = aB[r] * invB;
        }
    }
}

// ---------------------------------------------------------------------------
extern "C" void kernel_launch(void* const* d_in, const int* in_sizes, int n_in,
                              void* d_out, int out_size, void* d_ws, size_t ws_size,
                              hipStream_t stream) {
    const float* q = (const float*)d_in[0];
    const float* k = (const float*)d_in[1];
    const float* v = (const float*)d_in[2];
    const float* proj = (const float*)d_in[3];
    float* out = (float*)d_out;

    char* ws = (char*)d_ws;
    char* sblk = ws;                                   // 8MB (in-place -> S_used)
    char* kbf = ws + (8u << 20);                       // 8MB
    char* vbf = ws + (16u << 20);                      // 8MB
    float* z = (float*)(ws + (24u << 20));             // 256KB
    char* pbf = ws + (24u << 20) + (256u << 10);       // 8KB

    k_phase1<<<dim3(1024), dim3(256), 0, stream>>>(k, v, proj, sblk, kbf, vbf, z);
    k_scan<<<dim3(133), dim3(256), 0, stream>>>(sblk, z, proj, pbf);
    k_main<<<dim3(2048), dim3(256), 0, stream>>>(q, kbf, vbf, sblk, pbf, z, out);
}